// Round 5
// baseline (162.146 us; speedup 1.0000x reference)
//
#include <hip/hip_runtime.h>
#include <hip/hip_bf16.h>

// Problem constants (match reference)
#define B 8
#define S 2048
#define N 512
#define D 1024
#define MAX_W 32
#define MASK_FILL -1000.0f
#define G 8                        // spans per block (grouped by sorted end)

// native clang vector type — required by __builtin_nontemporal_store
typedef float vfloat4 __attribute__((ext_vector_type(4)));

// ---------------------------------------------------------------------------
// Kernel 1: per-batch rank sort of spans by end position.
// One block per batch, one thread per span; O(N^2) rank compare vs LDS keys
// (broadcast — conflict-free). order[b*N + rank] = original span index.
// Purpose: groups of G consecutive ranks have nearby ends -> small
// contiguous row union per block -> explicit register reuse in kernel 2.
// ---------------------------------------------------------------------------
__global__ __launch_bounds__(512) void sort_kernel(
    const int* __restrict__ spans,
    int* __restrict__ order)
{
    const int b = blockIdx.x;
    const int n = threadIdx.x;                 // span within batch (N=512)

    __shared__ unsigned short s_key[N];

    const int key = spans[2 * (b * N + n) + 1];  // end position (0..2046)
    s_key[n] = (unsigned short)key;
    __syncthreads();

    int rank = 0;
#pragma unroll 8
    for (int j = 0; j < N; ++j) {
        const int kj = (int)s_key[j];
        rank += (kj < key) | ((kj == key) & (j < n));
    }
    order[b * N + rank] = n;
}

// ---------------------------------------------------------------------------
// Kernel 2: fused logits + masked softmax + pooling for G spans per block.
//
// A span's valid rows are exactly [start, end] (contiguous: raw = end-w >= 0
// is implied by start >= 0 for w <= width). The block streams rows
// [lo, hi] = [min start, max end] over its G sorted-by-end spans:
//   pass 1: logits l[s] = dot(seq[b,s,:], att_w)+b  — one row per WAVE
//           (lane covers 4 float4 slices, shuffle-reduce, no barriers)
//   pass 2: per-span softmax over 32 entries (half-wave per span);
//           masked entries get weight exactly 0 (expf(-1000-m)==0 in fp32,
//           identical to the reference)
//   pass 3: re-stream rows (L2-hot), accumulate all G span outputs in
//           registers: acc[g] += attn[g][end_g - s] * row_s
// This removes the standalone 64 MB logits pass AND cuts gather volume
// ~2x via explicit register reuse (scheduling-based L2 reuse failed in R4:
// with ~8 blocks/CU half the grid is co-resident, order doesn't matter).
// ---------------------------------------------------------------------------
__global__ __launch_bounds__(256) void fused_kernel(
    const float* __restrict__ seq,
    const int*   __restrict__ spans,
    const float* __restrict__ att_w,
    const float* __restrict__ att_b,
    const int*   __restrict__ order,
    float* __restrict__ out)
{
    const int b   = blockIdx.x & 7;        // batch -> XCD affinity
    const int grp = blockIdx.x >> 3;       // 0..63 (N/G per batch)

    __shared__ int   s_n[G], s_start[G], s_end[G];
    __shared__ int   s_lohi[2];
    __shared__ float s_logit[S];           // 8 KB, index s - lo (worst case)
    __shared__ float s_attn[G][MAX_W];     // 1 KB

    const int tid  = threadIdx.x;
    const int lane = tid & 63;
    const int wid  = tid >> 6;             // wave 0..3

    if (tid < G) {
        const int rank = grp * G + tid;
        const int n    = order[b * N + rank];
        s_n[tid]     = n;
        s_start[tid] = spans[2 * (b * N + n) + 0];
        s_end[tid]   = spans[2 * (b * N + n) + 1];
    }
    __syncthreads();
    if (tid == 0) {
        int lo = s_start[0], hi = s_end[0];
#pragma unroll
        for (int g = 1; g < G; ++g) {
            lo = min(lo, s_start[g]);
            hi = max(hi, s_end[g]);
        }
        s_lohi[0] = lo; s_lohi[1] = hi;
    }
    __syncthreads();
    const int lo = s_lohi[0], hi = s_lohi[1];

    const float* sb = seq + (size_t)b * S * D;

    // ---- pass 1: logits for rows [lo,hi]; one row per wave, no barriers ----
    {
        const float4* wp = (const float4*)att_w;
        const float4 w0 = wp[lane];
        const float4 w1 = wp[lane + 64];
        const float4 w2 = wp[lane + 128];
        const float4 w3 = wp[lane + 192];
        const float bias = att_b[0];

        for (int s = lo + wid; s <= hi; s += 4) {
            const float4* rp = (const float4*)(sb + (size_t)s * D);
            const float4 a0 = rp[lane];
            const float4 a1 = rp[lane + 64];
            const float4 a2 = rp[lane + 128];
            const float4 a3 = rp[lane + 192];
            float acc = a0.x * w0.x + a0.y * w0.y + a0.z * w0.z + a0.w * w0.w
                      + a1.x * w1.x + a1.y * w1.y + a1.z * w1.z + a1.w * w1.w
                      + a2.x * w2.x + a2.y * w2.y + a2.z * w2.z + a2.w * w2.w
                      + a3.x * w3.x + a3.y * w3.y + a3.z * w3.z + a3.w * w3.w;
#pragma unroll
            for (int off = 32; off > 0; off >>= 1)
                acc += __shfl_down(acc, off);
            if (lane == 0)
                s_logit[s - lo] = acc + bias;
        }
    }
    __syncthreads();

    // ---- pass 2: softmax per span; half-wave per span (8 half-waves = G) --
    {
        const int g = tid >> 5;            // 0..7
        const int k = tid & 31;
        const int en  = s_end[g];
        const int wdt = en - s_start[g];
        const bool valid = (k <= wdt);
        const int  li = max(en - k - lo, 0);       // clamp: no OOB LDS read
        const float l = valid ? s_logit[li] : MASK_FILL;

        float m = l;
#pragma unroll
        for (int off = 16; off > 0; off >>= 1)
            m = fmaxf(m, __shfl_down(m, off, 32));
        m = __shfl(m, 0, 32);

        const float p = __expf(l - m);

        float sum = p;
#pragma unroll
        for (int off = 16; off > 0; off >>= 1)
            sum += __shfl_down(sum, off, 32);
        sum = __shfl(sum, 0, 32);

        s_attn[g][k] = p / sum;            // exactly 0 for masked entries
    }
    __syncthreads();

    // ---- pass 3: pooling; thread tid owns float4 column slice #tid ----
    int st_r[G], en_r[G];
#pragma unroll
    for (int g = 0; g < G; ++g) { st_r[g] = s_start[g]; en_r[g] = s_end[g]; }

    float4 acc[G];
#pragma unroll
    for (int g = 0; g < G; ++g) acc[g] = make_float4(0.f, 0.f, 0.f, 0.f);

    for (int s = lo; s <= hi; ++s) {
        const float4 v = ((const float4*)(sb + (size_t)s * D))[tid];
#pragma unroll
        for (int g = 0; g < G; ++g) {
            if (s >= st_r[g] && s <= en_r[g]) {   // same for all lanes
                const float a = s_attn[g][en_r[g] - s];
                acc[g].x += a * v.x;
                acc[g].y += a * v.y;
                acc[g].z += a * v.z;
                acc[g].w += a * v.w;
            }
        }
    }

    // ---- store (non-temporal: streaming output, keep L2 for seq) ----
#pragma unroll
    for (int g = 0; g < G; ++g) {
        vfloat4 va;
        va.x = acc[g].x; va.y = acc[g].y; va.z = acc[g].z; va.w = acc[g].w;
        vfloat4* op = ((vfloat4*)(out + (size_t)(b * N + s_n[g]) * D)) + tid;
        __builtin_nontemporal_store(va, op);
    }
}

// ---------------------------------------------------------------------------
extern "C" void kernel_launch(void* const* d_in, const int* in_sizes, int n_in,
                              void* d_out, int out_size, void* d_ws, size_t ws_size,
                              hipStream_t stream)
{
    const float* seq    = (const float*)d_in[0];  // (B,S,D) f32
    const int*   spans  = (const int*)  d_in[1];  // (B,N,2) i32
    const float* att_w  = (const float*)d_in[2];  // (D,1)   f32
    const float* att_b  = (const float*)d_in[3];  // (1,)    f32

    float* out   = (float*)d_out;                 // (B,N,D) f32
    int*   order = (int*)d_ws;                    // (B,N) i32 scratch

    sort_kernel<<<B, 512, 0, stream>>>(spans, order);
    fused_kernel<<<(B * N) / G, 256, 0, stream>>>(seq, spans, att_w, att_b,
                                                  order, out);
}

// Round 6
// 128.827 us; speedup vs baseline: 1.2586x; 1.2586x over previous
//
#include <hip/hip_runtime.h>
#include <hip/hip_bf16.h>

// Problem constants (match reference)
#define B 8
#define S 2048
#define N 512
#define D 1024
#define MAX_W 32
#define MASK_FILL -1000.0f
#define G 8                         // spans per pool block (sorted grouping)
#define LOGITS_BLOCKS 2048          // (B*S)/8 rows per block

// native clang vector type — required by __builtin_nontemporal_store
typedef float vfloat4 __attribute__((ext_vector_type(4)));

// ---------------------------------------------------------------------------
// Kernel 1 (fused dispatch): logits + per-batch span sort.
//   blocks [0, 2048): logits[b,s] = dot(seq[b,s,:], att_w) + att_b
//     8 rows per block, one row per 64-lane wave, shuffle-reduce.
//     Massively parallel (16K waves) -> HBM-bound, also warms L3 with seq.
//   blocks [2048, 2056): rank-sort spans of batch (blockIdx-2048) by end.
//     O(N^2) rank compare vs LDS keys (broadcast, conflict-free).
//     order[b*N + rank] = original span index.
// No dependency between the two halves; merged to save a dispatch.
// ---------------------------------------------------------------------------
__global__ __launch_bounds__(512) void prep_kernel(
    const float* __restrict__ seq,
    const float* __restrict__ att_w,
    const float* __restrict__ att_b,
    const int*   __restrict__ spans,
    float* __restrict__ logits,
    int*   __restrict__ order)
{
    __shared__ unsigned short s_key[N];

    if (blockIdx.x < LOGITS_BLOCKS) {
        const int row  = blockIdx.x * 8 + (threadIdx.x >> 6);
        const int lane = threadIdx.x & 63;

        const float4* rp = (const float4*)(seq + (size_t)row * D);
        const float4* wp = (const float4*)att_w;

        float acc = 0.0f;
#pragma unroll
        for (int k = 0; k < 4; ++k) {
            const float4 a = rp[lane + 64 * k];
            const float4 w = wp[lane + 64 * k];
            acc += a.x * w.x + a.y * w.y + a.z * w.z + a.w * w.w;
        }
#pragma unroll
        for (int off = 32; off > 0; off >>= 1)
            acc += __shfl_down(acc, off);
        if (lane == 0)
            logits[row] = acc + att_b[0];
    } else {
        const int b = blockIdx.x - LOGITS_BLOCKS;
        const int n = threadIdx.x;                  // span within batch

        const int key = spans[2 * (b * N + n) + 1]; // end position
        s_key[n] = (unsigned short)key;
        __syncthreads();

        int rank = 0;
#pragma unroll 8
        for (int j = 0; j < N; ++j) {
            const int kj = (int)s_key[j];
            rank += (kj < key) | ((kj == key) & (j < n));
        }
        order[b * N + rank] = n;
    }
}

// ---------------------------------------------------------------------------
// Kernel 2: grouped pool. G=8 spans (consecutive sorted ranks -> overlapping
// row ranges) per block; the block streams the contiguous union [lo,hi] ONCE
// and keeps all 8 accumulators in registers (explicit reuse, ~2-3x traffic
// cut vs per-span blocks; R4 showed scheduling-based L2 reuse doesn't work).
//
// R5 lesson (latency-bound at 8 waves/CU): the row loop is unrolled x4 with
// independent loads (32 KB in flight/CU), and each group is guarded by a
// block-uniform branch so chunks outside [st_g, en_g] cost ~nothing (execz).
//
// Softmax: masked entries get weight exactly 0 (expf(-1000-m)==0 in fp32,
// identical to the reference), and valid rows are exactly [start,end]
// (start>=0 makes raw_idx>=0 automatic), so padded/out-of-span rows
// contribute exactly 0 — bit-identical to the reference semantics.
// ---------------------------------------------------------------------------
__global__ __launch_bounds__(256) void pool_kernel(
    const float* __restrict__ seq,
    const int*   __restrict__ spans,
    const float* __restrict__ logits,
    const int*   __restrict__ order,
    float* __restrict__ out)
{
    const int b   = blockIdx.x & 7;        // batch -> XCD affinity
    const int grp = blockIdx.x >> 3;       // 0..63

    __shared__ int   s_n[G], s_st[G], s_en[G];
    __shared__ int   s_lohi[2];
    __shared__ float s_attn[G][MAX_W];

    const int tid = threadIdx.x;

    if (tid < G) {
        const int n = order[b * N + grp * G + tid];
        s_n[tid]  = n;
        s_st[tid] = spans[2 * (b * N + n) + 0];
        s_en[tid] = spans[2 * (b * N + n) + 1];
    }
    __syncthreads();

    if (tid == 0) {
        int lo = s_st[0], hi = s_en[0];
#pragma unroll
        for (int g = 1; g < G; ++g) {
            lo = min(lo, s_st[g]);
            hi = max(hi, s_en[g]);
        }
        s_lohi[0] = lo; s_lohi[1] = hi;
    }

    // softmax: 8 half-waves, g = tid>>5, k = tid&31; logits is 64 KB and
    // L2/L3-resident from prep_kernel.
    {
        const int g = tid >> 5, k = tid & 31;
        const int en  = s_en[g];
        const int wdt = en - s_st[g];
        const bool valid = (k <= wdt);
        const int  idx = max(en - k, 0);
        const float l = valid ? logits[b * S + idx] : MASK_FILL;

        float m = l;
#pragma unroll
        for (int off = 16; off > 0; off >>= 1)
            m = fmaxf(m, __shfl_down(m, off, 32));
        m = __shfl(m, 0, 32);

        const float p = __expf(l - m);

        float sum = p;
#pragma unroll
        for (int off = 16; off > 0; off >>= 1)
            sum += __shfl_down(sum, off, 32);
        sum = __shfl(sum, 0, 32);

        s_attn[g][k] = p / sum;            // exactly 0 for masked entries
    }
    __syncthreads();

    const int lo = s_lohi[0], hi = s_lohi[1];

    int st[G], en[G];
#pragma unroll
    for (int g = 0; g < G; ++g) { st[g] = s_st[g]; en[g] = s_en[g]; }

    const float* sb = seq + (size_t)b * S * D;

    float4 acc[G];
#pragma unroll
    for (int g = 0; g < G; ++g) acc[g] = make_float4(0.f, 0.f, 0.f, 0.f);

    for (int s = lo; s <= hi; s += 4) {
        // 4 independent loads in flight (rows clamped to hi; logical row
        // index beyond hi gets weight 0, so clamped loads are harmless)
        const int r1 = min(s + 1, hi);
        const int r2 = min(s + 2, hi);
        const int r3 = min(s + 3, hi);
        const float4 v0 = ((const float4*)(sb + (size_t)s  * D))[tid];
        const float4 v1 = ((const float4*)(sb + (size_t)r1 * D))[tid];
        const float4 v2 = ((const float4*)(sb + (size_t)r2 * D))[tid];
        const float4 v3 = ((const float4*)(sb + (size_t)r3 * D))[tid];

#pragma unroll
        for (int g = 0; g < G; ++g) {
            const int t = st[g], e = en[g];
            if (s <= e && s + 3 >= t) {    // block-uniform -> execz skip
                const int o0 = e - s;
                const float a0 = (s     >= t && o0     >= 0) ? s_attn[g][o0 & 31]       : 0.f;
                const float a1 = (s + 1 >= t && o0 - 1 >= 0) ? s_attn[g][(o0 - 1) & 31] : 0.f;
                const float a2 = (s + 2 >= t && o0 - 2 >= 0) ? s_attn[g][(o0 - 2) & 31] : 0.f;
                const float a3 = (s + 3 >= t && o0 - 3 >= 0) ? s_attn[g][(o0 - 3) & 31] : 0.f;
                acc[g].x += a0 * v0.x + a1 * v1.x + a2 * v2.x + a3 * v3.x;
                acc[g].y += a0 * v0.y + a1 * v1.y + a2 * v2.y + a3 * v3.y;
                acc[g].z += a0 * v0.z + a1 * v1.z + a2 * v2.z + a3 * v3.z;
                acc[g].w += a0 * v0.w + a1 * v1.w + a2 * v2.w + a3 * v3.w;
            }
        }
    }

    // streaming output: non-temporal stores, keep L2/L3 for seq
#pragma unroll
    for (int g = 0; g < G; ++g) {
        vfloat4 va;
        va.x = acc[g].x; va.y = acc[g].y; va.z = acc[g].z; va.w = acc[g].w;
        vfloat4* op = ((vfloat4*)(out + (size_t)(b * N + s_n[g]) * D)) + tid;
        __builtin_nontemporal_store(va, op);
    }
}

// ---------------------------------------------------------------------------
extern "C" void kernel_launch(void* const* d_in, const int* in_sizes, int n_in,
                              void* d_out, int out_size, void* d_ws, size_t ws_size,
                              hipStream_t stream)
{
    const float* seq    = (const float*)d_in[0];  // (B,S,D) f32
    const int*   spans  = (const int*)  d_in[1];  // (B,N,2) i32
    const float* att_w  = (const float*)d_in[2];  // (D,1)   f32
    const float* att_b  = (const float*)d_in[3];  // (1,)    f32

    float* out    = (float*)d_out;                // (B,N,D) f32
    float* logits = (float*)d_ws;                 // (B,S)   f32 scratch
    int*   order  = (int*)((char*)d_ws + B * S * sizeof(float)); // (B,N) i32

    prep_kernel<<<LOGITS_BLOCKS + B, 512, 0, stream>>>(seq, att_w, att_b,
                                                       spans, logits, order);
    pool_kernel<<<(B * N) / G, 256, 0, stream>>>(seq, spans, logits, order, out);
}